// Round 2
// baseline (495.169 us; speedup 1.0000x reference)
//
#include <hip/hip_runtime.h>

#define LMAX   2048
#define NFFT   4096
#define DMODEL 512
#define NSTATE 64
#define NBATCH 16
#define PI_D   3.14159265358979323846

// ws layout: [0, 16KB): twiddle table tw[2048] (float2), exp(-2*pi*i*j/4096)
//            [16KB, 16KB+16MB): Kd[512][4096] float2 (4096-pt spectrum of padded K)

__device__ __forceinline__ float2 cmul(float2 a, float2 b) {
  return make_float2(a.x*b.x - a.y*b.y, a.x*b.y + a.y*b.x);
}

// Stockham radix-2 FFT in LDS. 256 threads. Ping-pongs src/dst each stage;
// returned pointer is the result buffer (== src iff LOGN even).
// sign = -1: forward (e^{-i}); sign = +1: inverse WITHOUT the 1/N scale.
// Twiddle table tw[j] = exp(-2*pi*i*j/4096); index = p << (12-LOGN+stage).
template<int LOGN>
__device__ float2* fft_lds(float2* src, float2* dst, const float2* tw, int sign, int tid) {
  constexpr int N = 1 << LOGN;
  for (int stage = 0; stage < LOGN; ++stage) {
    const int s = 1 << stage;
    const int m = 1 << (LOGN - 1 - stage);     // N/(2s)
    const int twshift = 12 - (LOGN - stage);
    __syncthreads();
    #pragma unroll
    for (int i = tid; i < (N >> 1); i += 256) {
      const int q = i & (s - 1);
      const int p = i >> stage;
      float2 a = src[i];                       // q + s*p == i
      float2 b = src[i + (m << stage)];        // q + s*(p+m)
      float2 w = tw[p << twshift];
      float wy = (sign > 0) ? -w.y : w.y;
      float2 sum = make_float2(a.x + b.x, a.y + b.y);
      float2 dif = make_float2(a.x - b.x, a.y - b.y);
      float2 wd  = make_float2(dif.x*w.x - dif.y*wy, dif.x*wy + dif.y*w.x);
      const int o = q + ((p << 1) << stage);   // q + s*2p
      dst[o]     = sum;
      dst[o + s] = wd;
    }
    float2* t = src; src = dst; dst = t;
  }
  __syncthreads();
  return src;
}

__global__ void twiddle_init(float2* tw) {
  int j = blockIdx.x * blockDim.x + threadIdx.x;
  if (j < NFFT/2) {
    double ang = -2.0 * PI_D * (double)j / (double)NFFT;
    double s, c;
    sincos(ang, &s, &c);
    tw[j] = make_float2((float)c, (float)s);
  }
}

// One block per channel d: Cauchy kernel at 2048 roots of unity -> forward
// 2048-pt FFT (== reference ifft + [0,L-1..1] reorder, scaled 1/L) -> real K
// -> zero-pad -> forward 4096-pt FFT -> Kd[d][0..4095].
__global__ __launch_bounds__(256) void s4_kernel_K(
    const float* __restrict__ p_ri, const float* __restrict__ q_ri,
    const float* __restrict__ lam_ri, const float* __restrict__ B_ri,
    const float* __restrict__ Ct_ri, const float* __restrict__ log_step,
    const float2* __restrict__ twg, float2* __restrict__ Kd)
{
  __shared__ float2 A[NFFT];
  __shared__ float2 Bb[NFFT];
  __shared__ float2 tw[NFFT/2];
  const int d = blockIdx.x;
  const int tid = threadIdx.x;

  for (int j = tid; j < NFFT/2; j += 256) tw[j] = twg[j];

  // Per-d weight vectors parked in Bb; consumed before fft_lds clobbers Bb
  // (stage-0 __syncthreads orders the clobber after the Cauchy loop).
  float2* lam = Bb;
  float2* w00 = Bb + 64;
  float2* w01 = Bb + 128;
  float2* w10 = Bb + 192;
  float2* w11 = Bb + 256;
  if (tid < NSTATE) {
    const int n = tid;
    float2 la = make_float2(lam_ri[2*n], lam_ri[2*n+1]);
    float2 pp = make_float2(p_ri[2*n],  p_ri[2*n+1]);
    float2 qq = make_float2(q_ri[2*n],  q_ri[2*n+1]);
    float2 Bv = make_float2(B_ri[(d*NSTATE+n)*2],  B_ri[(d*NSTATE+n)*2+1]);
    float2 Cv = make_float2(Ct_ri[(d*NSTATE+n)*2], Ct_ri[(d*NSTATE+n)*2+1]);
    lam[n] = la;
    // a0 = conj(Ct), a1 = conj(q), b0 = B, b1 = p
    w00[n] = make_float2(Cv.x*Bv.x + Cv.y*Bv.y, Cv.x*Bv.y - Cv.y*Bv.x);
    w01[n] = make_float2(Cv.x*pp.x + Cv.y*pp.y, Cv.x*pp.y - Cv.y*pp.x);
    w10[n] = make_float2(qq.x*Bv.x + qq.y*Bv.y, qq.x*Bv.y - qq.y*Bv.x);
    w11[n] = make_float2(qq.x*pp.x + qq.y*pp.y, qq.x*pp.y - qq.y*pp.x);
  }
  __syncthreads();

  const float two_over_step = 2.0f / expf(log_step[d]);
  for (int l = tid; l < LMAX; l += 256) {
    float theta = (float)(2.0 * PI_D / (double)LMAX) * (float)l;
    float si, co;
    sincosf(theta, &si, &co);
    // den = 1 + omega ; c = 2/den ; g = (2/step)*(1-omega)/den
    float dx = 1.f + co, dy = si;
    float inv = 1.0f / (dx*dx + dy*dy);
    float2 c = make_float2(2.f*dx*inv, -2.f*dy*inv);
    float nx = 1.f - co, ny = -si;
    float2 g = make_float2(two_over_step * (nx*dx + ny*dy) * inv,
                           two_over_step * (ny*dx - nx*dy) * inv);
    float2 k00 = {0,0}, k01 = {0,0}, k10 = {0,0}, k11 = {0,0};
    #pragma unroll 8
    for (int n = 0; n < NSTATE; ++n) {
      float2 la = lam[n];
      float rr = g.x - la.x, ri = g.y - la.y;
      float rinv = 1.0f / (rr*rr + ri*ri);
      float2 r = make_float2(rr*rinv, -ri*rinv);
      float2 a;
      a = w00[n]; k00.x += a.x*r.x - a.y*r.y; k00.y += a.x*r.y + a.y*r.x;
      a = w01[n]; k01.x += a.x*r.x - a.y*r.y; k01.y += a.x*r.y + a.y*r.x;
      a = w10[n]; k10.x += a.x*r.x - a.y*r.y; k10.y += a.x*r.y + a.y*r.x;
      a = w11[n]; k11.x += a.x*r.x - a.y*r.y; k11.y += a.x*r.y + a.y*r.x;
    }
    // at = c * (k00 - k01*k10/(1+k11))
    float2 s1 = make_float2(1.f + k11.x, k11.y);
    float sinv = 1.0f / (s1.x*s1.x + s1.y*s1.y);
    float2 t = cmul(k01, k10);
    float2 tdiv = make_float2((t.x*s1.x + t.y*s1.y)*sinv, (t.y*s1.x - t.x*s1.y)*sinv);
    A[l] = cmul(c, make_float2(k00.x - tdiv.x, k00.y - tdiv.y));
  }

  // K[k] = Re(FWD_DFT_2048(at_roots)[k]) / 2048
  float2* res = fft_lds<11>(A, Bb, tw, -1, tid);   // 11 stages (odd) -> res == Bb
  for (int k = tid; k < NFFT; k += 256) {
    float kr = (k < LMAX) ? res[k].x * (1.0f / LMAX) : 0.0f;
    A[k] = make_float2(kr, 0.f);
  }
  float2* res2 = fft_lds<12>(A, Bb, tw, -1, tid);  // 12 stages (even) -> res2 == A
  for (int f = tid; f < NFFT; f += 256)
    Kd[(size_t)d * NFFT + f] = res2[f];
}

// One block per (batch, channel-pair). Packs two real channels into one
// complex FFT, multiplies by Kd in the frequency domain, one inverse FFT
// yields both real outputs (Re/Im), adds D*u, writes y.
__global__ __launch_bounds__(256) void s4_kernel_U(
    const float* __restrict__ u, const float* __restrict__ Dp,
    const float2* __restrict__ twg, const float2* __restrict__ Kd,
    float* __restrict__ out)
{
  __shared__ float2 A[NFFT];
  __shared__ float2 Bb[NFFT];
  __shared__ float2 tw[NFFT/2];
  const int dp = blockIdx.x;           // 0..255 channel pair (fast dim -> L2 locality on Kd)
  const int b  = blockIdx.y;           // 0..15
  const int d0 = dp * 2;
  const int tid = threadIdx.x;

  for (int j = tid; j < NFFT/2; j += 256) tw[j] = twg[j];

  float2 ur[8];
  const float* ubase = u + ((size_t)b * LMAX) * DMODEL + d0;
  #pragma unroll
  for (int k = 0; k < 8; ++k) {
    const int l = tid + 256*k;
    float2 v = *(const float2*)(ubase + (size_t)l * DMODEL);
    ur[k] = v;
    A[l] = v;                          // z = u[d0] + i*u[d0+1]
  }
  #pragma unroll
  for (int k = 8; k < 16; ++k) A[tid + 256*k] = make_float2(0.f, 0.f);

  float2* Z = fft_lds<12>(A, Bb, tw, -1, tid);     // Z == A

  const float2* K0 = Kd + (size_t)d0 * NFFT;
  const float2* K1 = K0 + NFFT;
  #pragma unroll
  for (int k = 0; k < 16; ++k) {
    const int f = tid + 256*k;
    float2 zf = Z[f];
    float2 zr = Z[(NFFT - f) & (NFFT - 1)];
    // U0 = (zf + conj(zr))/2 ; U1 = -i/2 * (zf - conj(zr))
    float2 u0 = make_float2(0.5f*(zf.x + zr.x), 0.5f*(zf.y - zr.y));
    float2 du = make_float2(zf.x - zr.x, zf.y + zr.y);
    float2 u1 = make_float2(0.5f*du.y, -0.5f*du.x);
    float2 y0 = cmul(u0, K0[f]);
    float2 y1 = cmul(u1, K1[f]);
    Bb[f] = make_float2(y0.x - y1.y, y0.y + y1.x);  // W = Y0 + i*Y1
  }

  float2* W = fft_lds<12>(Bb, A, tw, +1, tid);     // result == Bb

  const float D0 = Dp[d0], D1 = Dp[d0 + 1];
  float* obase = out + ((size_t)b * LMAX) * DMODEL + d0;
  const float scale = 1.0f / NFFT;
  #pragma unroll
  for (int k = 0; k < 8; ++k) {
    const int l = tid + 256*k;
    float2 w = W[l];
    float2 o = make_float2(w.x*scale + D0*ur[k].x, w.y*scale + D1*ur[k].y);
    *(float2*)(obase + (size_t)l * DMODEL) = o;
  }
}

extern "C" void kernel_launch(void* const* d_in, const int* in_sizes, int n_in,
                              void* d_out, int out_size, void* d_ws, size_t ws_size,
                              hipStream_t stream) {
  const float* u        = (const float*)d_in[0];
  const float* p_ri     = (const float*)d_in[1];
  const float* q_ri     = (const float*)d_in[2];
  const float* lam_ri   = (const float*)d_in[3];
  const float* B_ri     = (const float*)d_in[4];
  const float* Ct_ri    = (const float*)d_in[5];
  const float* Dp       = (const float*)d_in[6];
  const float* log_step = (const float*)d_in[7];
  float* out = (float*)d_out;

  float2* tw = (float2*)d_ws;
  float2* Kd = (float2*)((char*)d_ws + (NFFT/2) * sizeof(float2));

  twiddle_init<<<8, 256, 0, stream>>>(tw);
  s4_kernel_K<<<DMODEL, 256, 0, stream>>>(p_ri, q_ri, lam_ri, B_ri, Ct_ri,
                                          log_step, tw, Kd);
  s4_kernel_U<<<dim3(DMODEL/2, NBATCH), 256, 0, stream>>>(u, Dp, tw, Kd, out);
}

// Round 3
// 337.814 us; speedup vs baseline: 1.4658x; 1.4658x over previous
//
#include <hip/hip_runtime.h>

#define LMAX   2048
#define NFFT   4096
#define DMODEL 512
#define NSTATE 64
#define NBATCH 16
#define PI_D   3.14159265358979323846
#define NT_U   512
#define NT_K   512

// ws layout: [0, 16KB): twiddle table tw[2048] (float2), exp(-2*pi*i*j/4096)
//            [16KB, ...): Kd[512][4096] float2 (4096-pt spectrum of padded K)

// LDS physical index swizzle (float2 granularity). Bijective within any
// 1024-element FFT sub-span (flips only low 5 bits with bits [9:5]) and
// applied to EVERY LDS element access -> correctness-neutral. Turns the
// early-stage Stockham scatter-writes (stride 8/64 float2: 32-way bank
// conflict) into <=4-way.
__device__ __forceinline__ int swz(int a) { return a ^ ((a >> 5) & 31); }

__device__ __forceinline__ float2 cmul(float2 a, float2 b) {
  return make_float2(a.x*b.x - a.y*b.y, a.x*b.y + a.y*b.x);
}

// tw[j] = exp(-2*pi*i*j/4096), table holds j in [0,2048); idx in [0,4096)
// via half-circle sign trick.
__device__ __forceinline__ float2 twget(const float2* tw, int idx) {
  float2 w = tw[idx & 2047];
  if (idx & 2048) { w.x = -w.x; w.y = -w.y; }
  return w;
}

// Stockham FFT in LDS, radix-8 stages (+ final radix-4 when LOGN%3==2).
// General butterfly: dst[q + r*s*p + j*s] = sum_k x_k e^{-2pi i jk/r} * W^{jp},
// W = e^{-2pi i s/N}, x_k = src[i + k*N/r], i = q + s*p.
// INV=true: conjugate twiddles and internal constants (no 1/N scale).
// Returns result buffer; for LOGN in {11,12} (4 stages) result == src.
template<int LOGN, bool INV, int NT>
__device__ float2* fft_lds(float2* src, float2* dst, const float2* tw, int tid) {
  constexpr int N = 1 << LOGN;
  constexpr int NS8 = LOGN / 3;     // radix-8 stage count (12->4, 11->3)
  constexpr int TSH = 12 - LOGN;    // twiddle table is for N=4096
  const float r2 = 0.70710678118654752f;
  int s = 1;
  #pragma unroll
  for (int st = 0; st < NS8; ++st) {
    __syncthreads();
    for (int i = tid; i < (N >> 3); i += NT) {
      const int q  = i & (s - 1);
      const int ps = i - q;                   // p*s
      float2 x[8];
      #pragma unroll
      for (int k = 0; k < 8; ++k) x[k] = src[swz(i + k * (N >> 3))];
      float2 E0,E1,E2,E3,O0,O1,O2,O3;
      { // DFT4 of even taps (x0,x2,x4,x6)
        float2 u0 = make_float2(x[0].x+x[4].x, x[0].y+x[4].y);
        float2 v0 = make_float2(x[0].x-x[4].x, x[0].y-x[4].y);
        float2 u1 = make_float2(x[2].x+x[6].x, x[2].y+x[6].y);
        float2 v1 = make_float2(x[2].x-x[6].x, x[2].y-x[6].y);
        E0 = make_float2(u0.x+u1.x, u0.y+u1.y);
        E2 = make_float2(u0.x-u1.x, u0.y-u1.y);
        if (!INV) { E1 = make_float2(v0.x+v1.y, v0.y-v1.x); E3 = make_float2(v0.x-v1.y, v0.y+v1.x); }
        else      { E1 = make_float2(v0.x-v1.y, v0.y+v1.x); E3 = make_float2(v0.x+v1.y, v0.y-v1.x); }
      }
      { // DFT4 of odd taps (x1,x3,x5,x7)
        float2 u0 = make_float2(x[1].x+x[5].x, x[1].y+x[5].y);
        float2 v0 = make_float2(x[1].x-x[5].x, x[1].y-x[5].y);
        float2 u1 = make_float2(x[3].x+x[7].x, x[3].y+x[7].y);
        float2 v1 = make_float2(x[3].x-x[7].x, x[3].y-x[7].y);
        O0 = make_float2(u0.x+u1.x, u0.y+u1.y);
        O2 = make_float2(u0.x-u1.x, u0.y-u1.y);
        if (!INV) { O1 = make_float2(v0.x+v1.y, v0.y-v1.x); O3 = make_float2(v0.x-v1.y, v0.y+v1.x); }
        else      { O1 = make_float2(v0.x-v1.y, v0.y+v1.x); O3 = make_float2(v0.x+v1.y, v0.y-v1.x); }
      }
      // odd part * omega^j, omega = e^{-+2pi i/8}
      float2 o1 = (!INV) ? make_float2((O1.x+O1.y)*r2, (O1.y-O1.x)*r2)
                         : make_float2((O1.x-O1.y)*r2, (O1.y+O1.x)*r2);
      float2 o2 = (!INV) ? make_float2(O2.y, -O2.x) : make_float2(-O2.y, O2.x);
      float2 o3 = (!INV) ? make_float2((O3.y-O3.x)*r2, -(O3.x+O3.y)*r2)
                         : make_float2(-(O3.x+O3.y)*r2, (O3.x-O3.y)*r2);
      float2 y[8];
      y[0] = make_float2(E0.x+O0.x, E0.y+O0.y);
      y[4] = make_float2(E0.x-O0.x, E0.y-O0.y);
      y[1] = make_float2(E1.x+o1.x, E1.y+o1.y);
      y[5] = make_float2(E1.x-o1.x, E1.y-o1.y);
      y[2] = make_float2(E2.x+o2.x, E2.y+o2.y);
      y[6] = make_float2(E2.x-o2.x, E2.y-o2.y);
      y[3] = make_float2(E3.x+o3.x, E3.y+o3.y);
      y[7] = make_float2(E3.x-o3.x, E3.y-o3.y);
      const int idx1  = ps << TSH;
      const int obase = q + (ps << 3);
      dst[swz(obase)] = y[0];
      #pragma unroll
      for (int j = 1; j < 8; ++j) {
        float2 w = twget(tw, j * idx1);
        if (INV) w.y = -w.y;
        dst[swz(obase + j * s)] = cmul(w, y[j]);
      }
    }
    s <<= 3;
    float2* t = src; src = dst; dst = t;
  }
  if constexpr (LOGN % 3 == 2) {   // final radix-4 stage (LOGN=11)
    __syncthreads();
    for (int i = tid; i < (N >> 2); i += NT) {
      const int q  = i & (s - 1);
      const int ps = i - q;
      float2 x0 = src[swz(i)];
      float2 x1 = src[swz(i + (N >> 2))];
      float2 x2 = src[swz(i + (N >> 1))];
      float2 x3 = src[swz(i + 3 * (N >> 2))];
      float2 u0 = make_float2(x0.x+x2.x, x0.y+x2.y), v0 = make_float2(x0.x-x2.x, x0.y-x2.y);
      float2 u1 = make_float2(x1.x+x3.x, x1.y+x3.y), v1 = make_float2(x1.x-x3.x, x1.y-x3.y);
      float2 y0 = make_float2(u0.x+u1.x, u0.y+u1.y);
      float2 y2 = make_float2(u0.x-u1.x, u0.y-u1.y);
      float2 y1, y3;
      if (!INV) { y1 = make_float2(v0.x+v1.y, v0.y-v1.x); y3 = make_float2(v0.x-v1.y, v0.y+v1.x); }
      else      { y1 = make_float2(v0.x-v1.y, v0.y+v1.x); y3 = make_float2(v0.x+v1.y, v0.y-v1.x); }
      const int idx1  = ps << TSH;
      const int obase = q + (ps << 2);
      float2 w1 = twget(tw, idx1), w2 = twget(tw, 2*idx1), w3 = twget(tw, 3*idx1);
      if (INV) { w1.y=-w1.y; w2.y=-w2.y; w3.y=-w3.y; }
      dst[swz(obase)]         = y0;
      dst[swz(obase + s)]     = cmul(w1, y1);
      dst[swz(obase + 2*s)]   = cmul(w2, y2);
      dst[swz(obase + 3*s)]   = cmul(w3, y3);
    }
    float2* t = src; src = dst; dst = t;
  }
  __syncthreads();
  return src;
}

__global__ void twiddle_init(float2* tw) {
  int j = blockIdx.x * blockDim.x + threadIdx.x;
  if (j < NFFT/2) {
    double ang = -2.0 * PI_D * (double)j / (double)NFFT;
    double s, c;
    sincos(ang, &s, &c);
    tw[j] = make_float2((float)c, (float)s);
  }
}

// One block per channel d: Cauchy kernel at 2048 roots -> fwd 2048-pt FFT
// (== reference ifft + [0,L-1..1] reorder, scaled 1/L) -> real K -> pad
// -> fwd 4096-pt FFT -> Kd[d][0..4095].
__global__ __launch_bounds__(NT_K) void s4_kernel_K(
    const float* __restrict__ p_ri, const float* __restrict__ q_ri,
    const float* __restrict__ lam_ri, const float* __restrict__ B_ri,
    const float* __restrict__ Ct_ri, const float* __restrict__ log_step,
    const float2* __restrict__ twg, float2* __restrict__ Kd)
{
  __shared__ float2 A[NFFT];
  __shared__ float2 Bb[NFFT];
  __shared__ float2 tw[NFFT/2];
  const int d = blockIdx.x;
  const int tid = threadIdx.x;

  for (int j = tid; j < NFFT/2; j += NT_K) tw[j] = twg[j];

  // per-d weight vectors parked in Bb; consumed in the Cauchy loop, which
  // completes before fft stage-0's barrier lets Bb be clobbered.
  float2* lam = Bb;
  float2* w00 = Bb + 64;
  float2* w01 = Bb + 128;
  float2* w10 = Bb + 192;
  float2* w11 = Bb + 256;
  if (tid < NSTATE) {
    const int n = tid;
    float2 la = make_float2(lam_ri[2*n], lam_ri[2*n+1]);
    float2 pp = make_float2(p_ri[2*n],  p_ri[2*n+1]);
    float2 qq = make_float2(q_ri[2*n],  q_ri[2*n+1]);
    float2 Bv = make_float2(B_ri[(d*NSTATE+n)*2],  B_ri[(d*NSTATE+n)*2+1]);
    float2 Cv = make_float2(Ct_ri[(d*NSTATE+n)*2], Ct_ri[(d*NSTATE+n)*2+1]);
    lam[n] = la;
    // a0 = conj(Ct), a1 = conj(q), b0 = B, b1 = p
    w00[n] = make_float2(Cv.x*Bv.x + Cv.y*Bv.y, Cv.x*Bv.y - Cv.y*Bv.x);
    w01[n] = make_float2(Cv.x*pp.x + Cv.y*pp.y, Cv.x*pp.y - Cv.y*pp.x);
    w10[n] = make_float2(qq.x*Bv.x + qq.y*Bv.y, qq.x*Bv.y - qq.y*Bv.x);
    w11[n] = make_float2(qq.x*pp.x + qq.y*pp.y, qq.x*pp.y - qq.y*pp.x);
  }
  __syncthreads();

  const float two_over_step = 2.0f / expf(log_step[d]);
  for (int l = tid; l < LMAX; l += NT_K) {
    float theta = (float)(2.0 * PI_D / (double)LMAX) * (float)l;
    float si, co;
    sincosf(theta, &si, &co);
    float dx = 1.f + co, dy = si;
    float inv = 1.0f / (dx*dx + dy*dy);
    float2 c = make_float2(2.f*dx*inv, -2.f*dy*inv);
    float nx = 1.f - co, ny = -si;
    float2 g = make_float2(two_over_step * (nx*dx + ny*dy) * inv,
                           two_over_step * (ny*dx - nx*dy) * inv);
    float2 k00 = {0,0}, k01 = {0,0}, k10 = {0,0}, k11 = {0,0};
    #pragma unroll 8
    for (int n = 0; n < NSTATE; ++n) {
      float2 la = lam[n];
      float rr = g.x - la.x, ri = g.y - la.y;
      float rinv = 1.0f / (rr*rr + ri*ri);
      float2 r = make_float2(rr*rinv, -ri*rinv);
      float2 a;
      a = w00[n]; k00.x += a.x*r.x - a.y*r.y; k00.y += a.x*r.y + a.y*r.x;
      a = w01[n]; k01.x += a.x*r.x - a.y*r.y; k01.y += a.x*r.y + a.y*r.x;
      a = w10[n]; k10.x += a.x*r.x - a.y*r.y; k10.y += a.x*r.y + a.y*r.x;
      a = w11[n]; k11.x += a.x*r.x - a.y*r.y; k11.y += a.x*r.y + a.y*r.x;
    }
    float2 s1 = make_float2(1.f + k11.x, k11.y);
    float sinv = 1.0f / (s1.x*s1.x + s1.y*s1.y);
    float2 t = cmul(k01, k10);
    float2 tdiv = make_float2((t.x*s1.x + t.y*s1.y)*sinv, (t.y*s1.x - t.x*s1.y)*sinv);
    A[swz(l)] = cmul(c, make_float2(k00.x - tdiv.x, k00.y - tdiv.y));
  }

  // K[k] = Re(FWD_DFT_2048(at_roots)[k]) / 2048
  float2* res = fft_lds<11, false, NT_K>(A, Bb, tw, tid);   // res == A
  for (int k = tid; k < NFFT; k += NT_K) {
    float kr = (k < LMAX) ? res[swz(k)].x * (1.0f / LMAX) : 0.0f;
    Bb[swz(k)] = make_float2(kr, 0.f);
  }
  float2* res2 = fft_lds<12, false, NT_K>(Bb, A, tw, tid);  // res2 == Bb
  for (int f = tid; f < NFFT; f += NT_K)
    Kd[(size_t)d * NFFT + f] = res2[swz(f)];
}

// One block per (batch, channel-pair). XCD-swizzled so the 32 consecutive
// channel-pairs that share u/out cachelines and Kd panels land on one XCD's
// L2. Packs two real channels into one complex FFT; freq-domain multiply;
// one inverse FFT yields both real outputs (Re/Im); adds D*u.
__global__ __launch_bounds__(NT_U) void s4_kernel_U(
    const float* __restrict__ u, const float* __restrict__ Dp,
    const float2* __restrict__ twg, const float2* __restrict__ Kd,
    float* __restrict__ out)
{
  __shared__ float2 A[NFFT];
  __shared__ float2 Bb[NFFT];
  __shared__ float2 tw[NFFT/2];
  const int bxr = blockIdx.x;                    // 0..255
  const int dp  = (bxr & 7) * 32 + (bxr >> 3);   // XCD c owns dp [c*32,(c+1)*32)
  const int b   = blockIdx.y;
  const int d0  = dp * 2;
  const int tid = threadIdx.x;

  for (int j = tid; j < NFFT/2; j += NT_U) tw[j] = twg[j];

  float2 ur[4];
  const float* ubase = u + ((size_t)b * LMAX) * DMODEL + d0;
  #pragma unroll
  for (int k = 0; k < 4; ++k) {
    const int l = tid + NT_U * k;
    float2 v = *(const float2*)(ubase + (size_t)l * DMODEL);
    ur[k] = v;
    A[swz(l)] = v;                               // z = u[d0] + i*u[d0+1]
  }
  #pragma unroll
  for (int k = 4; k < 8; ++k) A[swz(tid + NT_U * k)] = make_float2(0.f, 0.f);

  float2* Z = fft_lds<12, false, NT_U>(A, Bb, tw, tid);    // Z == A

  const float2* K0 = Kd + (size_t)d0 * NFFT;
  const float2* K1 = K0 + NFFT;
  #pragma unroll
  for (int k = 0; k < 8; ++k) {
    const int f = tid + NT_U * k;
    float2 zf = Z[swz(f)];
    float2 zr = Z[swz((NFFT - f) & (NFFT - 1))];
    // U0 = (zf + conj(zr))/2 ; U1 = -i/2 * (zf - conj(zr))
    float2 u0 = make_float2(0.5f*(zf.x + zr.x), 0.5f*(zf.y - zr.y));
    float2 du = make_float2(zf.x - zr.x, zf.y + zr.y);
    float2 u1 = make_float2(0.5f*du.y, -0.5f*du.x);
    float2 y0 = cmul(u0, K0[f]);
    float2 y1 = cmul(u1, K1[f]);
    Bb[swz(f)] = make_float2(y0.x - y1.y, y0.y + y1.x);    // W = Y0 + i*Y1
  }

  float2* W = fft_lds<12, true, NT_U>(Bb, A, tw, tid);     // W == Bb

  const float D0 = Dp[d0], D1 = Dp[d0 + 1];
  float* obase = out + ((size_t)b * LMAX) * DMODEL + d0;
  const float scale = 1.0f / NFFT;
  #pragma unroll
  for (int k = 0; k < 4; ++k) {
    const int l = tid + NT_U * k;
    float2 w = W[swz(l)];
    float2 o = make_float2(w.x*scale + D0*ur[k].x, w.y*scale + D1*ur[k].y);
    *(float2*)(obase + (size_t)l * DMODEL) = o;
  }
}

extern "C" void kernel_launch(void* const* d_in, const int* in_sizes, int n_in,
                              void* d_out, int out_size, void* d_ws, size_t ws_size,
                              hipStream_t stream) {
  const float* u        = (const float*)d_in[0];
  const float* p_ri     = (const float*)d_in[1];
  const float* q_ri     = (const float*)d_in[2];
  const float* lam_ri   = (const float*)d_in[3];
  const float* B_ri     = (const float*)d_in[4];
  const float* Ct_ri    = (const float*)d_in[5];
  const float* Dp       = (const float*)d_in[6];
  const float* log_step = (const float*)d_in[7];
  float* out = (float*)d_out;

  float2* tw = (float2*)d_ws;
  float2* Kd = (float2*)((char*)d_ws + (NFFT/2) * sizeof(float2));

  twiddle_init<<<8, 256, 0, stream>>>(tw);
  s4_kernel_K<<<DMODEL, NT_K, 0, stream>>>(p_ri, q_ri, lam_ri, B_ri, Ct_ri,
                                           log_step, tw, Kd);
  s4_kernel_U<<<dim3(DMODEL/2, NBATCH), NT_U, 0, stream>>>(u, Dp, tw, Kd, out);
}